// Round 6
// baseline (568.419 us; speedup 1.0000x reference)
//
#include <hip/hip_runtime.h>

#define NB 4096

typedef __attribute__((ext_vector_type(8))) __bf16 bf16x8;
typedef __attribute__((ext_vector_type(4))) float  f32x4;

__device__ __forceinline__ float gelu_fast(float x){
    float x2 = x * x;
    float y  = x * (0.79788456f + 0.03567741f * x2);
    float e  = __expf(2.0f * y);
    float t  = 1.0f - 2.0f / (e + 1.0f);
    return 0.5f * x * (1.0f + t);
}
__device__ __forceinline__ unsigned short f2bf(float x){
    unsigned b = __float_as_uint(x);
    b += 0x7fffu + ((b >> 16) & 1u);
    return (unsigned short)(b >> 16);
}

// ---------------- pack offsets (elements) ----------------
#define O_WP0  0
#define O_WP1  40960
#define O_WP2  368640
#define O_PROJ 696320
#define O_VAL1 761856
#define O_POS1 827392
#define O_RES1 892928
#define O_VAL2 958464
#define O_RES2 991232
#define O_POS2 1515520
#define O_MIX  1519616
#define PK_TOTAL 1523712

__device__ __forceinline__ unsigned short pack_std_elem(const float* W, int N, int t){
    int j = t & 7, lane = (t >> 3) & 63, rest = t >> 9;
    int ntcnt = N >> 4;
    int nt = rest % ntcnt, kk = rest / ntcnt;
    int n = nt*16 + (lane & 15), k = kk*32 + ((lane >> 4) << 3) + j;
    return f2bf(W[k * N + n]);
}
__device__ __forceinline__ unsigned short pack_pad_elem(const float* W, int Nreal, int t){
    int j = t & 7, lane = (t >> 3) & 63, kk = t >> 9;
    int n = lane & 15, k = kk*32 + ((lane >> 4) << 3) + j;
    return (n < Nreal) ? f2bf(W[k * Nreal + n]) : (unsigned short)0;
}

__global__ __launch_bounds__(256) void pack_weights(
    const float* __restrict__ W0, const float* __restrict__ W1, const float* __restrict__ W2,
    const float* __restrict__ proj_w, const float* __restrict__ val_w1,
    const float* __restrict__ pos_w1, const float* __restrict__ res_w1,
    const float* __restrict__ val_w2, const float* __restrict__ res_w2,
    const float* __restrict__ pos_w2, const float* __restrict__ mix_w,
    unsigned short* __restrict__ pk)
{
    int idx = blockIdx.x * 256 + threadIdx.x;
    if (idx >= PK_TOTAL) return;
    if (idx < O_WP1){
        int t = idx;
        int j = t & 7, lane = (t >> 3) & 63, gnt = (t >> 9) & 15, kk = t >> 13;
        int co = gnt*16 + (lane & 15), ci = (lane >> 4)*8 + j;
        pk[idx] = f2bf(W0[co*160 + ci*5 + kk]);
    } else if (idx < O_WP2){
        int t = idx - O_WP1;
        int j = t & 7, lane = (t >> 3) & 63, gnt = (t >> 9) & 15, kk = t >> 13;
        int kc = kk >> 3, s = kk & 7;
        int co = gnt*16 + (lane & 15), ci = s*32 + (lane >> 4)*8 + j;
        pk[idx] = f2bf(W1[co*1280 + ci*5 + kc]);
    } else if (idx < O_PROJ){
        int t = idx - O_WP2;
        int j = t & 7, lane = (t >> 3) & 63, gnt = (t >> 9) & 15, kk = t >> 13;
        int kc = kk >> 3, s = kk & 7;
        int co = gnt*16 + (lane & 15), ci = s*32 + (lane >> 4)*8 + j;
        pk[idx] = f2bf(W2[co*1280 + ci*5 + kc]);
    }
    else if (idx < O_VAL1) pk[idx] = pack_std_elem(proj_w, 256, idx - O_PROJ);
    else if (idx < O_POS1) pk[idx] = pack_std_elem(val_w1, 256, idx - O_VAL1);
    else if (idx < O_RES1) pk[idx] = pack_std_elem(pos_w1, 256, idx - O_POS1);
    else if (idx < O_VAL2) pk[idx] = pack_std_elem(res_w1, 256, idx - O_RES1);
    else if (idx < O_RES2) pk[idx] = pack_std_elem(val_w2, 128, idx - O_VAL2);
    else if (idx < O_POS2) pk[idx] = pack_std_elem(res_w2, 2048, idx - O_RES2);
    else if (idx < O_MIX)  pk[idx] = pack_pad_elem(pos_w2, 4, idx - O_POS2);
    else                   pk[idx] = pack_pad_elem(mix_w, 2, idx - O_MIX);
}

// ---------------- Kernel 1: MFMA conv, weights-as-A (vector epilogue) ----------------
// GEMM role swap: A = packed weights (M=co), B = hidden state (N=t). Fragment
// layouts are symmetric so all load addresses are identical to the previous
// version; C/D now has 4 consecutive co per lane -> ds_write_b64 epilogue.
#define HT_S 264
#define XT_S 32

__global__ __launch_bounds__(256, 2) void conv_mfma_kernel(
    const float* __restrict__ A,
    const float* __restrict__ B0, const float* __restrict__ B1, const float* __restrict__ B2,
    const unsigned short* __restrict__ wp0, const unsigned short* __restrict__ wp1,
    const unsigned short* __restrict__ wp2,
    unsigned short* __restrict__ pooled)
{
    __shared__ unsigned short xt[2][68 * XT_S];
    __shared__ unsigned short ht[2][68 * HT_S];

    const int tid  = threadIdx.x;
    const int b0   = blockIdx.x * 2;
    const int w    = tid >> 6;
    const int lane = tid & 63;
    const int l15  = lane & 15;
    const int q    = lane >> 4;
    const int w4   = w << 2;
    const int q8   = q << 3;
    const int q4   = q << 2;
    const int lane8 = lane << 3;

    for (int i = tid; i < 4 * HT_S; i += 256){
        int r = i / HT_S, c = i - r * HT_S;
        int rr = (r < 2 ? r : r + 64);
        ht[0][rr * HT_S + c] = 0;
        ht[1][rr * HT_S + c] = 0;
    }
    if (tid < 128){
        int r = tid >> 5, c = tid & 31;
        int rr = (r < 2 ? r : r + 64);
        xt[0][rr * XT_S + c] = 0;
        xt[1][rr * XT_S + c] = 0;
    }
    #pragma unroll
    for (int bb = 0; bb < 2; ++bb){
        const float* Ab = A + (size_t)(b0 + bb) * 2048;
        int e0 = tid << 3;
        int t = e0 >> 5, c = e0 & 31;
        const float4* p = (const float4*)(Ab + e0);
        float4 v0 = p[0], v1 = p[1];
        union { unsigned short u[8]; bf16x8 v; } pkv;
        pkv.u[0]=f2bf(v0.x); pkv.u[1]=f2bf(v0.y); pkv.u[2]=f2bf(v0.z); pkv.u[3]=f2bf(v0.w);
        pkv.u[4]=f2bf(v1.x); pkv.u[5]=f2bf(v1.y); pkv.u[6]=f2bf(v1.z); pkv.u[7]=f2bf(v1.w);
        *(bf16x8*)&xt[bb][(t + 2) * XT_S + c] = pkv.v;
    }
    __syncthreads();

    f32x4 acc0[4][4], acc1[4][4];   // [mt = co-tile][nt = t-tile]

#define ZERO2 \
    { _Pragma("unroll") for (int mt = 0; mt < 4; ++mt) \
      _Pragma("unroll") for (int nt = 0; nt < 4; ++nt){ \
          acc0[mt][nt] = (f32x4){0.f,0.f,0.f,0.f}; acc1[mt][nt] = (f32x4){0.f,0.f,0.f,0.f}; } }
// hidden-state B-frags (same addresses as before; nt = t-tile)
#define LOADH_X(BUF, BB, KC) \
    { _Pragma("unroll") for (int nt = 0; nt < 4; ++nt) \
          BUF[nt] = *(const bf16x8*)&xt[BB][((nt << 4) + l15 + (KC)) * XT_S + q8]; }
#define LOADH(BUF, BB, KK) \
    { _Pragma("unroll") for (int nt = 0; nt < 4; ++nt) \
          BUF[nt] = *(const bf16x8*)&ht[BB][((nt << 4) + l15 + ((KK) >> 3)) * HT_S + (((KK) & 7) << 5) + q8]; }
// weight A-frags (same addresses as before; mt = co-tile)
#define LOADW(BUF, KK, WP) \
    { _Pragma("unroll") for (int mt = 0; mt < 4; ++mt) \
          BUF[mt] = *(const bf16x8*)((WP) + ((((KK) << 4) + w4 + mt) << 9) + lane8); }
#define MF(ACC, WF, HF) \
    { _Pragma("unroll") for (int mt = 0; mt < 4; ++mt) \
      _Pragma("unroll") for (int nt = 0; nt < 4; ++nt) \
          ACC[mt][nt] = __builtin_amdgcn_mfma_f32_16x16x32_bf16(WF[mt], HF[nt], ACC[mt][nt], 0, 0, 0); }
// vector epilogue: 4 consecutive co per lane -> one b64 write per tile
#define EPI(ACC, BB, BIAS) \
    { _Pragma("unroll") for (int mt = 0; mt < 4; ++mt){ \
        int cob = ((w4 + mt) << 4) + q4; \
        float4 bv = *(const float4*)&(BIAS)[cob]; \
        _Pragma("unroll") for (int nt = 0; nt < 4; ++nt){ \
            int t = (nt << 4) + l15; \
            unsigned u0 = (unsigned)f2bf(gelu_fast(ACC[mt][nt][0] + bv.x)) \
                        | ((unsigned)f2bf(gelu_fast(ACC[mt][nt][1] + bv.y)) << 16); \
            unsigned u1 = (unsigned)f2bf(gelu_fast(ACC[mt][nt][2] + bv.z)) \
                        | ((unsigned)f2bf(gelu_fast(ACC[mt][nt][3] + bv.w)) << 16); \
            uint2 uu; uu.x = u0; uu.y = u1; \
            *(uint2*)&ht[BB][(t + 2) * HT_S + cob] = uu; } } }

#define CONV_LAYER2(WP) \
    { bf16x8 Wf0[4], Wf1[4], H0a[4], H1a[4], H0b[4], H1b[4]; \
      LOADW(Wf0, 0, WP); \
      LOADH(H0a, 0, 0); LOADH(H1a, 1, 0); \
      for (int kk = 0; kk < 38; kk += 2){ \
          LOADW(Wf1, kk + 1, WP); \
          LOADH(H0b, 0, kk + 1); \
          MF(acc0, Wf0, H0a); \
          LOADH(H1b, 1, kk + 1); \
          MF(acc1, Wf0, H1a); \
          LOADW(Wf0, kk + 2, WP); \
          LOADH(H0a, 0, kk + 2); \
          MF(acc0, Wf1, H0b); \
          LOADH(H1a, 1, kk + 2); \
          MF(acc1, Wf1, H1b); \
      } \
      LOADW(Wf1, 39, WP); \
      LOADH(H0b, 0, 39); \
      MF(acc0, Wf0, H0a); \
      LOADH(H1b, 1, 39); \
      MF(acc1, Wf0, H1a); \
      MF(acc0, Wf1, H0b); \
      MF(acc1, Wf1, H1b); }

    // ---- conv0 ----
    ZERO2;
    {
        bf16x8 Wf0[4], Wf1[4], Xa[4], Ya[4];
        LOADW(Wf0, 0, wp0);
        LOADH_X(Xa, 0, 0); LOADH_X(Ya, 1, 0);
        #pragma unroll
        for (int kc = 0; kc < 5; ++kc){
            if (kc + 1 < 5) LOADW(Wf1, kc + 1, wp0);
            MF(acc0, Wf0, Xa);
            MF(acc1, Wf0, Ya);
            if (kc + 1 < 5){
                LOADH_X(Xa, 0, kc + 1); LOADH_X(Ya, 1, kc + 1);
                #pragma unroll
                for (int mt = 0; mt < 4; ++mt) Wf0[mt] = Wf1[mt];
            }
        }
    }
    EPI(acc0, 0, B0);
    EPI(acc1, 1, B0);
    __syncthreads();

    // ---- conv1 ----
    ZERO2;
    CONV_LAYER2(wp1);
    __syncthreads();
    EPI(acc0, 0, B1);
    EPI(acc1, 1, B1);
    __syncthreads();

    // ---- conv2 + mean pool ----
    ZERO2;
    CONV_LAYER2(wp2);
    {
        #pragma unroll
        for (int bb = 0; bb < 2; ++bb){
            #pragma unroll
            for (int mt = 0; mt < 4; ++mt){
                int cob = ((w4 + mt) << 4) + q4;
                float4 bv = *(const float4*)&B2[cob];
                f32x4 s = (f32x4){0.f,0.f,0.f,0.f};
                #pragma unroll
                for (int nt = 0; nt < 4; ++nt){
                    f32x4 a = bb == 0 ? acc0[mt][nt] : acc1[mt][nt];
                    s[0] += gelu_fast(a[0] + bv.x);
                    s[1] += gelu_fast(a[1] + bv.y);
                    s[2] += gelu_fast(a[2] + bv.z);
                    s[3] += gelu_fast(a[3] + bv.w);
                }
                // reduce across l15 (t within tile); co fixed per (q, r)
                #pragma unroll
                for (int r = 0; r < 4; ++r){
                    float v = s[r];
                    v += __shfl_xor(v, 1);
                    v += __shfl_xor(v, 2);
                    v += __shfl_xor(v, 4);
                    v += __shfl_xor(v, 8);
                    s[r] = v;
                }
                if (l15 == 0){
                    unsigned u0 = (unsigned)f2bf(s[0] * (1.0f/64.0f)) | ((unsigned)f2bf(s[1] * (1.0f/64.0f)) << 16);
                    unsigned u1 = (unsigned)f2bf(s[2] * (1.0f/64.0f)) | ((unsigned)f2bf(s[3] * (1.0f/64.0f)) << 16);
                    uint2 uu; uu.x = u0; uu.y = u1;
                    *(uint2*)&pooled[(size_t)(b0 + bb) * 256 + cob] = uu;
                }
            }
        }
    }
}

// ---------------- Kernel 2a: heads stages A-C, 16 batches/block ----------------
#define AS 264

__global__ __launch_bounds__(256) void heads_a_kernel(
    const unsigned short* __restrict__ pooled,
    const float* __restrict__ proj_b, const float* __restrict__ val_b1,
    const float* __restrict__ pos_b1, const float* __restrict__ res_b1,
    const float* __restrict__ val_b2, const float* __restrict__ pos_b2,
    const float* __restrict__ mix_b,
    const unsigned short* __restrict__ pk,
    unsigned short* __restrict__ rh, float* __restrict__ meta,
    float* __restrict__ accums)
{
    __shared__ unsigned short pb [16 * AS];
    __shared__ unsigned short eb [16 * AS];
    __shared__ unsigned short vb [16 * AS];
    __shared__ unsigned short phb[16 * AS];
    __shared__ unsigned short rhb[16 * AS];
    __shared__ float av [16 * 132];
    __shared__ float avs[16 * 132];
    __shared__ float psort[16][4];
    __shared__ int   rank [16][4];
    __shared__ float qsh  [16][2];
    __shared__ float mlsh [16][2];
    __shared__ float sposh[16][4];

    const int tid  = threadIdx.x;
    const int b0   = blockIdx.x * 16;
    const int w    = tid >> 6;
    const int lane = tid & 63;
    const int l15  = lane & 15;
    const int q    = lane >> 4;
    const int q8   = q << 3;
    const int q4   = q << 2;

    {
        int g = tid >> 4, seg = tid & 15;
        const unsigned short* ps = pooled + ((size_t)(b0 + g) << 8) + (seg << 4);
        bf16x8 a0 = *(const bf16x8*)ps;
        bf16x8 a1 = *(const bf16x8*)(ps + 8);
        *(bf16x8*)&pb[g * AS + (seg << 4)]     = a0;
        *(bf16x8*)&pb[g * AS + (seg << 4) + 8] = a1;
    }
    __syncthreads();

#define HGEMM256(ASRC, GOFF, BIAS, DST) \
    { f32x4 hacc[4]; \
      _Pragma("unroll") for (int nt = 0; nt < 4; ++nt) hacc[nt] = (f32x4){0.f,0.f,0.f,0.f}; \
      _Pragma("unroll") for (int kk = 0; kk < 8; ++kk){ \
          bf16x8 af = *(const bf16x8*)&(ASRC)[l15 * AS + (kk << 5) + q8]; \
          _Pragma("unroll") for (int nt = 0; nt < 4; ++nt){ \
              bf16x8 bfr = *(const bf16x8*)(pk + (GOFF) + (size_t)((((kk << 4) + (w << 2) + nt) << 6) + lane) * 8); \
              hacc[nt] = __builtin_amdgcn_mfma_f32_16x16x32_bf16(af, bfr, hacc[nt], 0, 0, 0); } } \
      _Pragma("unroll") for (int nt = 0; nt < 4; ++nt){ \
          int n = (w << 6) + (nt << 4) + l15; \
          float bv = (BIAS)[n]; \
          _Pragma("unroll") for (int r = 0; r < 4; ++r) \
              (DST)[(q4 + r) * AS + n] = f2bf(gelu_fast(hacc[nt][r] + bv)); } }

    HGEMM256(pb, O_PROJ, proj_b, eb);
    __syncthreads();

    HGEMM256(eb, O_VAL1, val_b1, vb);
    HGEMM256(eb, O_POS1, pos_b1, phb);
    HGEMM256(eb, O_RES1, res_b1, rhb);
    __syncthreads();

    {
        f32x4 acc2[2];
        #pragma unroll
        for (int nt = 0; nt < 2; ++nt) acc2[nt] = (f32x4){0.f,0.f,0.f,0.f};
        #pragma unroll
        for (int kk = 0; kk < 8; ++kk){
            bf16x8 af = *(const bf16x8*)&vb[l15 * AS + (kk << 5) + q8];
            #pragma unroll
            for (int nt = 0; nt < 2; ++nt){
                bf16x8 bfr = *(const bf16x8*)(pk + O_VAL2 + (size_t)(((kk*8 + w*2 + nt) << 6) + lane) * 8);
                acc2[nt] = __builtin_amdgcn_mfma_f32_16x16x32_bf16(af, bfr, acc2[nt], 0, 0, 0);
            }
        }
        #pragma unroll
        for (int nt = 0; nt < 2; ++nt){
            int j = (w << 5) + (nt << 4) + l15;
            float bv = val_b2[j];
            #pragma unroll
            for (int r = 0; r < 4; ++r)
                av[(q4 + r) * 132 + j] = acc2[nt][r] + bv;
        }
    }
    if (w == 0){
        f32x4 accp = (f32x4){0.f,0.f,0.f,0.f};
        #pragma unroll
        for (int kk = 0; kk < 8; ++kk){
            bf16x8 af  = *(const bf16x8*)&phb[l15 * AS + (kk << 5) + q8];
            bf16x8 bfr = *(const bf16x8*)(pk + O_POS2 + (size_t)((kk << 6) + lane) * 8);
            accp = __builtin_amdgcn_mfma_f32_16x16x32_bf16(af, bfr, accp, 0, 0, 0);
        }
        if (l15 < 4){
            float bv = pos_b2[l15];
            #pragma unroll
            for (int r = 0; r < 4; ++r){
                float raw = accp[r] + bv;
                sposh[q4 + r][l15] = 63.0f / (1.0f + __expf(-raw));
            }
        }
    } else if (w == 1){
        f32x4 accm = (f32x4){0.f,0.f,0.f,0.f};
        #pragma unroll
        for (int kk = 0; kk < 8; ++kk){
            bf16x8 af  = *(const bf16x8*)&eb[l15 * AS + (kk << 5) + q8];
            bf16x8 bfr = *(const bf16x8*)(pk + O_MIX + (size_t)((kk << 6) + lane) * 8);
            accm = __builtin_amdgcn_mfma_f32_16x16x32_bf16(af, bfr, accm, 0, 0, 0);
        }
        if (l15 < 2){
            #pragma unroll
            for (int r = 0; r < 4; ++r)
                mlsh[q4 + r][l15] = accm[r] + mix_b[l15];
        }
    }
    __syncthreads();

    if (tid < 16){
        int g = tid;
        float sv[4] = { sposh[g][0], sposh[g][1], sposh[g][2], sposh[g][3] };
        #pragma unroll
        for (int i = 0; i < 4; ++i){
            int r = 0;
            #pragma unroll
            for (int jj = 0; jj < 4; ++jj){
                r += (sv[jj] < sv[i]) ? 1 : 0;
                if (jj < i) r += (sv[jj] == sv[i]) ? 1 : 0;
            }
            rank[g][i] = r;
            psort[g][r] = sv[i];
        }
        psort[g][0] = 0.0f; psort[g][3] = 63.0f;
        float p1 = psort[g][1], p2 = psort[g][2];
        float g1 = p1, g2 = p2 - p1, g3 = 63.0f - p2;
        const float MG = 10.5f;
        float r1 = fmaxf(MG - g1, 0.f), r2 = fmaxf(MG - g2, 0.f), r3 = fmaxf(MG - g3, 0.f);
        float sp = (r1*r1 + r2*r2 + r3*r3) * (1.0f / 3.0f);
        float l0 = mlsh[g][0], l1 = mlsh[g][1];
        float m = fmaxf(l0, l1);
        float e0 = __expf(l0 - m), e1 = __expf(l1 - m);
        float inv = 1.0f / (e0 + e1);
        float q0 = e0 * inv, q1 = e1 * inv;
        qsh[g][0] = q0; qsh[g][1] = q1;
        float entc = q0 * logf(q0 + 1e-8f) + q1 * logf(q1 + 1e-8f);
        atomicAdd(&accums[2], entc);
        atomicAdd(&accums[3], q0);
        atomicAdd(&accums[4], q1);
        atomicAdd(&accums[5], sp);
    }
    __syncthreads();

    #pragma unroll
    for (int u2 = 0; u2 < 8; ++u2){
        int idx2 = tid * 8 + u2;
        int g = idx2 >> 7, j = idx2 & 127;
        avs[g * 132 + rank[g][j >> 5] * 32 + (j & 31)] = av[g * 132 + j];
    }
    __syncthreads();

    {
        int g = tid >> 4, c16 = (tid & 15) << 4;
        bf16x8 a0 = *(const bf16x8*)&rhb[g * AS + c16];
        bf16x8 a1 = *(const bf16x8*)&rhb[g * AS + c16 + 8];
        unsigned short* dst = rh + ((size_t)(b0 + g) << 8) + c16;
        *(bf16x8*)dst       = a0;
        *(bf16x8*)(dst + 8) = a1;
    }
    if (tid < 132){
        for (int g = 0; g < 16; ++g){
            float v;
            if (tid < 128)       v = avs[g * 132 + tid];
            else if (tid == 128) v = psort[g][1];
            else if (tid == 129) v = psort[g][2];
            else if (tid == 130) v = qsh[g][0];
            else                 v = qsh[g][1];
            meta[(size_t)(b0 + g) * 132 + tid] = v;
        }
    }
}

// ---------------- Kernel 2b: residual GEMM + interp + recon/L1 losses ----------------
__global__ __launch_bounds__(256) void resid_loss_kernel(
    const float* __restrict__ A, const unsigned short* __restrict__ rh,
    const float* __restrict__ res_b2, const unsigned short* __restrict__ pk,
    const float* __restrict__ meta, float* __restrict__ accums)
{
    __shared__ float ml[16 * 132];
    __shared__ float wred[4], wred2[4];

    const int tid  = threadIdx.x;
    const int w    = tid >> 6;
    const int lane = tid & 63;
    const int l15  = lane & 15;
    const int q    = lane >> 4;
    const int q8   = q << 3;
    const int q4   = q << 2;
    const int bg   = blockIdx.x >> 2;
    const int cc   = blockIdx.x & 3;
    const int b0   = bg << 4;

    for (int i = tid; i < 16 * 132; i += 256)
        ml[i] = meta[(size_t)b0 * 132 + i];
    __syncthreads();

    f32x4 acc[8];
    #pragma unroll
    for (int nt = 0; nt < 8; ++nt) acc[nt] = (f32x4){0.f,0.f,0.f,0.f};
    #pragma unroll
    for (int kk = 0; kk < 8; ++kk){
        bf16x8 af = *(const bf16x8*)(rh + ((size_t)(b0 + l15) << 8) + (kk << 5) + q8);
        #pragma unroll
        for (int nt = 0; nt < 8; ++nt){
            int ntg = (cc << 5) + (w << 3) + nt;
            bf16x8 bfr = *(const bf16x8*)(pk + O_RES2 + (size_t)((kk << 7) + ntg) * 512 + (lane << 3));
            acc[nt] = __builtin_amdgcn_mfma_f32_16x16x32_bf16(af, bfr, acc[nt], 0, 0, 0);
        }
    }

    float lsq = 0.f, ll1 = 0.f;
    #pragma unroll
    for (int nt = 0; nt < 8; ++nt){
        int e = (cc << 9) + (w << 7) + (nt << 4) + l15;
        float rbv = res_b2[e];
        int t = e >> 5, d = e & 31;
        float tf = (float)t;
        #pragma unroll
        for (int r = 0; r < 4; ++r){
            int g = q4 + r;
            const float* mg = &ml[g * 132];
            float p1 = mg[128], p2 = mg[129], q0 = mg[130], q1 = mg[131];
            float res = acc[nt][r] + rbv;
            int cnt = (p1 <= tf) + (p2 <= tf) + (tf >= 63.0f);
            int idx = cnt < 2 ? cnt : 2;
            float left  = idx == 0 ? 0.0f : (idx == 1 ? p1 : p2);
            float right = idx == 0 ? p1   : (idx == 1 ? p2 : 63.0f);
            float wgt = (tf - left) / (right - left + 1e-8f);
            wgt = fminf(fmaxf(wgt, 0.f), 1.f);
            float vl = mg[idx * 32 + d];
            float vr = mg[idx * 32 + 32 + d];
            float coarse = vl + wgt * (vr - vl);
            float a = A[((size_t)(b0 + g) << 11) + e];
            float fine = coarse + res;
            float recon = q0 * coarse + q1 * fine;
            float dd = recon - a;
            lsq += dd * dd;
            ll1 += fabsf(res);
        }
    }
    #pragma unroll
    for (int off = 32; off > 0; off >>= 1){
        lsq += __shfl_down(lsq, off);
        ll1 += __shfl_down(ll1, off);
    }
    if (lane == 0){ wred[w] = lsq; wred2[w] = ll1; }
    __syncthreads();
    if (tid == 0){
        atomicAdd(&accums[0], wred[0] + wred[1] + wred[2] + wred[3]);
        atomicAdd(&accums[1], wred2[0] + wred2[1] + wred2[2] + wred2[3]);
    }
}

// ---------------- Kernel 3: finalize ----------------
__global__ void finalize_kernel(const float* __restrict__ accums, float* __restrict__ out){
    float rs = accums[0], l1s = accums[1], ents = accums[2];
    float q0s = accums[3], q1s = accums[4], sps = accums[5];
    const float invN = 1.0f / (4096.0f * 2048.0f);
    const float invB = 1.0f / 4096.0f;
    float recon_loss = rs * invN;
    float l1   = l1s * invN;
    float ent  = -ents * invB;
    float mq0  = q0s * invB - 0.5f, mq1 = q1s * invB - 0.5f;
    float balance = mq0*mq0 + mq1*mq1;
    float spacing = sps * invB;
    out[0] = recon_loss + 0.05f*l1 + 0.01f*ent + 0.1f*balance + 0.1f*spacing;
}

extern "C" void kernel_launch(void* const* d_in, const int* in_sizes, int n_in,
                              void* d_out, int out_size, void* d_ws, size_t ws_size,
                              hipStream_t stream)
{
    const float* A      = (const float*)d_in[0];
    const float* W0     = (const float*)d_in[1];
    const float* B0     = (const float*)d_in[2];
    const float* W1     = (const float*)d_in[3];
    const float* B1     = (const float*)d_in[4];
    const float* W2     = (const float*)d_in[5];
    const float* B2     = (const float*)d_in[6];
    const float* proj_w = (const float*)d_in[7];
    const float* proj_b = (const float*)d_in[8];
    const float* val_w1 = (const float*)d_in[9];
    const float* val_b1 = (const float*)d_in[10];
    const float* val_w2 = (const float*)d_in[11];
    const float* val_b2 = (const float*)d_in[12];
    const float* pos_w1 = (const float*)d_in[13];
    const float* pos_b1 = (const float*)d_in[14];
    const float* pos_w2 = (const float*)d_in[15];
    const float* pos_b2 = (const float*)d_in[16];
    const float* res_w1 = (const float*)d_in[17];
    const float* res_b1 = (const float*)d_in[18];
    const float* res_w2 = (const float*)d_in[19];
    const float* res_b2 = (const float*)d_in[20];
    const float* mix_w  = (const float*)d_in[21];
    const float* mix_b  = (const float*)d_in[22];

    char* wsb = (char*)d_ws;
    float* accums = (float*)wsb;
    unsigned short* pooled = (unsigned short*)(wsb + 256);
    unsigned short* pkbuf  = (unsigned short*)(wsb + 256 + 2097152);
    unsigned short* rhbuf  = (unsigned short*)(wsb + 256 + 2097152 + (size_t)PK_TOTAL * 2);
    float* metabuf = (float*)(wsb + 256 + 2097152 + (size_t)PK_TOTAL * 2 + 2097152);

    hipMemsetAsync(accums, 0, 64 * sizeof(float), stream);

    hipLaunchKernelGGL(pack_weights, dim3((PK_TOTAL + 255) / 256), dim3(256), 0, stream,
                       W0, W1, W2, proj_w, val_w1, pos_w1, res_w1,
                       val_w2, res_w2, pos_w2, mix_w, pkbuf);

    hipLaunchKernelGGL(conv_mfma_kernel, dim3(NB / 2), dim3(256), 0, stream,
                       A, B0, B1, B2,
                       pkbuf + O_WP0, pkbuf + O_WP1, pkbuf + O_WP2, pooled);

    hipLaunchKernelGGL(heads_a_kernel, dim3(NB / 16), dim3(256), 0, stream,
                       pooled, proj_b, val_b1, pos_b1, res_b1, val_b2, pos_b2, mix_b,
                       pkbuf, rhbuf, metabuf, accums);

    hipLaunchKernelGGL(resid_loss_kernel, dim3(NB / 16 * 4), dim3(256), 0, stream,
                       A, rhbuf, res_b2, pkbuf, metabuf, accums);

    hipLaunchKernelGGL(finalize_kernel, dim3(1), dim3(1), 0, stream,
                       accums, (float*)d_out);
}